// Round 1
// baseline (327.054 us; speedup 1.0000x reference)
//
#include <hip/hip_runtime.h>

#define CLS 64
#define DIM 128
#define NROWS 262144
#define MARGIN 1.4f
#define EPSF 1e-6f

// ---------------- Phase A: per-block class sums / counts / sumsq ----------------
// LDS acc uses permuted slot layout: dim d -> slot (d%4)*32 + d/4.
// All downstream math is permutation-invariant over the dim axis, so we never unpermute.
__global__ __launch_bounds__(256) void phaseA(const float* __restrict__ emb,
                                              const int* __restrict__ tgt,
                                              float* __restrict__ psum,
                                              float* __restrict__ pcnt,
                                              float* __restrict__ psq,
                                              int rowsPerBlock) {
    __shared__ float acc[CLS * DIM];
    __shared__ float cnt[CLS];
    __shared__ float red[4];
    const int tid = threadIdx.x;

    for (int i = tid; i < CLS * DIM; i += 256) acc[i] = 0.f;
    if (tid < CLS) cnt[tid] = 0.f;
    __syncthreads();

    const int dl = tid & 31;          // dim-lane (covers 4 dims via float4)
    const int rowBase = blockIdx.x * rowsPerBlock;
    const int iters = rowsPerBlock >> 4;   // 16 rows per iteration
    int r = rowBase + (tid >> 5);          // row-lane 0..7

    const float4* __restrict__ embv = reinterpret_cast<const float4*>(emb);

    float4 va = embv[(size_t)r * 32 + dl];
    float4 vb = embv[(size_t)(r + 8) * 32 + dl];
    int ca = tgt[r];
    int cb = tgt[r + 8];

    float sq = 0.f;
    for (int it = 0; it < iters; ++it) {
        float4 xa = va, xb = vb;
        int ka = ca, kb = cb;
        int rn = r + 16;
        if (it + 1 < iters) {
            va = embv[(size_t)rn * 32 + dl];
            vb = embv[(size_t)(rn + 8) * 32 + dl];
            ca = tgt[rn];
            cb = tgt[rn + 8];
        }
        r = rn;

        sq += xa.x * xa.x + xa.y * xa.y + xa.z * xa.z + xa.w * xa.w;
        sq += xb.x * xb.x + xb.y * xb.y + xb.z * xb.z + xb.w * xb.w;

        float* rowA = &acc[ka * DIM];
        atomicAdd(&rowA[dl], xa.x);
        atomicAdd(&rowA[32 + dl], xa.y);
        atomicAdd(&rowA[64 + dl], xa.z);
        atomicAdd(&rowA[96 + dl], xa.w);
        float* rowB = &acc[kb * DIM];
        atomicAdd(&rowB[dl], xb.x);
        atomicAdd(&rowB[32 + dl], xb.y);
        atomicAdd(&rowB[64 + dl], xb.z);
        atomicAdd(&rowB[96 + dl], xb.w);
        if (dl == 0) {
            atomicAdd(&cnt[ka], 1.f);
            atomicAdd(&cnt[kb], 1.f);
        }
    }

    // wave reduce sumsq, then block reduce via LDS
    for (int o = 32; o > 0; o >>= 1) sq += __shfl_down(sq, o, 64);
    if ((tid & 63) == 0) red[tid >> 6] = sq;
    __syncthreads();

    float* __restrict__ myps = psum + (size_t)blockIdx.x * (CLS * DIM);
    for (int i = tid; i < CLS * DIM; i += 256) myps[i] = acc[i];
    if (tid < CLS) pcnt[blockIdx.x * CLS + tid] = cnt[tid];
    if (tid == 0) psq[blockIdx.x] = red[0] + red[1] + red[2] + red[3];
}

// ---------------- Phase B: reduce partials -> final sums/counts/sumsq ----------------
__global__ __launch_bounds__(256) void phaseB(const float* __restrict__ psum,
                                              const float* __restrict__ pcnt,
                                              const float* __restrict__ psq,
                                              float* __restrict__ fsum,
                                              float* __restrict__ fcnt,
                                              float* __restrict__ fsq,
                                              int NB) {
    __shared__ float red[8][32];
    const int tid = threadIdx.x;
    const int oo = tid & 31;
    const int kl = tid >> 5;
    const int o = blockIdx.x * 32 + oo;

    float s = 0.f;
    for (int k = kl; k < NB; k += 8) s += psum[(size_t)k * (CLS * DIM) + o];
    red[kl][oo] = s;
    __syncthreads();
    if (tid < 32) {
        float t = 0.f;
        for (int k = 0; k < 8; ++k) t += red[k][tid];
        fsum[o] = t;
    }

    if (blockIdx.x == 0) {
        if (tid >= 64 && tid < 128) {
            const int c = tid - 64;
            float t = 0.f;
            for (int k = 0; k < NB; ++k) t += pcnt[k * CLS + c];
            fcnt[c] = t;
        }
        if (tid >= 128 && tid < 192) {
            const int lane = tid - 128;
            float t = 0.f;
            for (int k = lane; k < NB; k += 64) t += psq[k];
            for (int off = 32; off > 0; off >>= 1) t += __shfl_down(t, off, 64);
            if (lane == 0) fsq[0] = t;
        }
    }
}

// ---------------- Phase C: centers, l2 identity, pairwise margin term ----------------
__device__ double blockReduceD(double v, double* scratch, int tid) {
    for (int o = 32; o > 0; o >>= 1) v += __shfl_down(v, o, 64);
    if ((tid & 63) == 0) scratch[tid >> 6] = v;
    __syncthreads();
    double t = 0.0;
    if (tid == 0) {
        for (int i = 0; i < 16; ++i) t += scratch[i];
    }
    __syncthreads();
    return t;
}

__global__ __launch_bounds__(1024) void phaseC(const float* __restrict__ fsum,
                                               const float* __restrict__ fcnt,
                                               const float* __restrict__ fsq,
                                               float* __restrict__ out) {
    __shared__ float cen[CLS][132];   // padded for conflict-free float4 reads
    __shared__ float cInv[CLS];
    __shared__ float cRaw[CLS];
    __shared__ double scratch[16];
    const int tid = threadIdx.x;

    if (tid < CLS) {
        float c = fcnt[tid];
        cRaw[tid] = c;
        cInv[tid] = 1.f / (c + EPSF);
    }
    __syncthreads();

    double s1 = 0.0, s2 = 0.0;
    for (int i = tid; i < CLS * DIM; i += 1024) {
        const int c = i >> 7;
        const int d = i & 127;
        float v = fsum[i];
        float ctr = v * cInv[c];
        cen[c][d] = ctr;
        s1 += (double)(v * ctr);
        s2 += (double)(cRaw[c] * ctr * ctr);
    }
    const double s1t = blockReduceD(s1, scratch, tid);
    const double s2t = blockReduceD(s2, scratch, tid);   // syncs ensure cen[] visible

    float ccp = 0.f;
    for (int q = tid; q < CLS * CLS; q += 1024) {
        const int a = q >> 6;
        const int b = q & 63;
        if (a == b) continue;
        const float4* __restrict__ pa = reinterpret_cast<const float4*>(cen[a]);
        const float4* __restrict__ pb = reinterpret_cast<const float4*>(cen[b]);
        float d2 = 0.f;
#pragma unroll
        for (int k = 0; k < 32; ++k) {
            float4 x = pa[k], y = pb[k];
            float dx = x.x - y.x, dy = x.y - y.y, dz = x.z - y.z, dw = x.w - y.w;
            d2 += dx * dx + dy * dy + dz * dz + dw * dw;
        }
        float val = fmaxf(MARGIN - sqrtf(d2 + EPSF), 0.f);
        ccp += val * val;
    }
    const double ccOrd = blockReduceD((double)ccp, scratch, tid);

    if (tid == 0) {
        double triu = ccOrd * 0.5;                     // ordered pairs -> a<b
        double ccv = triu / 64.0 * 63.0 / 2.0;
        double l2 = ((double)fsq[0] - 2.0 * s1t + s2t) / (double)NROWS;
        out[0] = (float)(l2 + ccv);
    }
}

extern "C" void kernel_launch(void* const* d_in, const int* in_sizes, int n_in,
                              void* d_out, int out_size, void* d_ws, size_t ws_size,
                              hipStream_t stream) {
    const float* emb = (const float*)d_in[0];
    const int* tgt = (const int*)d_in[1];
    float* out = (float*)d_out;

    char* ws = (char*)d_ws;
    float* fsum = (float*)ws;             // 8192 floats
    float* fcnt = fsum + CLS * DIM;       // 64 floats
    float* fsq = fcnt + CLS;              // 1 float

    int NB = 512;
    while (NB > 1) {
        size_t need = 65536 + (size_t)NB * ((size_t)CLS * DIM * 4 + CLS * 4 + 4);
        if (need <= ws_size) break;
        NB >>= 1;
    }
    float* psum = (float*)(ws + 65536);
    float* pcnt = psum + (size_t)NB * CLS * DIM;
    float* psq = pcnt + (size_t)NB * CLS;
    const int rowsPerBlock = NROWS / NB;

    phaseA<<<NB, 256, 0, stream>>>(emb, tgt, psum, pcnt, psq, rowsPerBlock);
    phaseB<<<256, 256, 0, stream>>>(psum, pcnt, psq, fsum, fcnt, fsq, NB);
    phaseC<<<1, 1024, 0, stream>>>(fsum, fcnt, fsq, out);
}

// Round 2
// 125.646 us; speedup vs baseline: 2.6030x; 2.6030x over previous
//
#include <hip/hip_runtime.h>

#define CLS 64
#define DIM 128
#define NROWS 262144
#define MARGIN 1.4f
#define EPSF 1e-6f
#define FIXSCALE 4194304.0f   // 2^22
#define INVFIX (1.0f / 4194304.0f)

// ---------------- Phase A: per-block class sums (int fixed-point) / counts / sumsq ----------------
// Integer ds_add_u32 atomics: native, fire-and-forget, exactly deterministic.
__global__ __launch_bounds__(256, 4) void phaseA(const float* __restrict__ emb,
                                                 const int* __restrict__ tgt,
                                                 float* __restrict__ psum,
                                                 float* __restrict__ pcnt,
                                                 float* __restrict__ psq,
                                                 int rowsPerBlock) {
    __shared__ int acc[CLS * DIM];
    __shared__ int cnt[CLS];
    __shared__ float red[4];
    const int tid = threadIdx.x;

    for (int i = tid; i < CLS * DIM; i += 256) acc[i] = 0;
    if (tid < CLS) cnt[tid] = 0;
    __syncthreads();

    const int dl = tid & 31;               // dim-lane (covers 4 dims via float4)
    const int rowBase = blockIdx.x * rowsPerBlock;
    const int iters = rowsPerBlock >> 4;   // 16 rows per iteration
    int r = rowBase + (tid >> 5);          // row-lane 0..7

    const float4* __restrict__ embv = reinterpret_cast<const float4*>(emb);

    float4 va = embv[(size_t)r * 32 + dl];
    float4 vb = embv[(size_t)(r + 8) * 32 + dl];
    int ca = tgt[r];
    int cb = tgt[r + 8];

    float sq = 0.f;
    for (int it = 0; it < iters; ++it) {
        float4 xa = va, xb = vb;
        int ka = ca, kb = cb;
        int rn = r + 16;
        if (it + 1 < iters) {
            va = embv[(size_t)rn * 32 + dl];
            vb = embv[(size_t)(rn + 8) * 32 + dl];
            ca = tgt[rn];
            cb = tgt[rn + 8];
        }
        r = rn;

        sq += xa.x * xa.x + xa.y * xa.y + xa.z * xa.z + xa.w * xa.w;
        sq += xb.x * xb.x + xb.y * xb.y + xb.z * xb.z + xb.w * xb.w;

        int* rowA = &acc[ka * DIM];
        atomicAdd(&rowA[dl],      __float2int_rn(xa.x * FIXSCALE));
        atomicAdd(&rowA[32 + dl], __float2int_rn(xa.y * FIXSCALE));
        atomicAdd(&rowA[64 + dl], __float2int_rn(xa.z * FIXSCALE));
        atomicAdd(&rowA[96 + dl], __float2int_rn(xa.w * FIXSCALE));
        int* rowB = &acc[kb * DIM];
        atomicAdd(&rowB[dl],      __float2int_rn(xb.x * FIXSCALE));
        atomicAdd(&rowB[32 + dl], __float2int_rn(xb.y * FIXSCALE));
        atomicAdd(&rowB[64 + dl], __float2int_rn(xb.z * FIXSCALE));
        atomicAdd(&rowB[96 + dl], __float2int_rn(xb.w * FIXSCALE));
        if (dl == 0) {
            atomicAdd(&cnt[ka], 1);
            atomicAdd(&cnt[kb], 1);
        }
    }

    // wave reduce sumsq, then block reduce via LDS
    for (int o = 32; o > 0; o >>= 1) sq += __shfl_down(sq, o, 64);
    if ((tid & 63) == 0) red[tid >> 6] = sq;
    __syncthreads();

    float* __restrict__ myps = psum + (size_t)blockIdx.x * (CLS * DIM);
    for (int i = tid; i < CLS * DIM; i += 256) myps[i] = (float)acc[i] * INVFIX;
    if (tid < CLS) pcnt[blockIdx.x * CLS + tid] = (float)cnt[tid];
    if (tid == 0) psq[blockIdx.x] = red[0] + red[1] + red[2] + red[3];
}

// ---------------- Phase B: reduce partials -> final sums/counts/sumsq ----------------
__global__ __launch_bounds__(256) void phaseB(const float* __restrict__ psum,
                                              const float* __restrict__ pcnt,
                                              const float* __restrict__ psq,
                                              float* __restrict__ fsum,
                                              float* __restrict__ fcnt,
                                              float* __restrict__ fsq,
                                              int NB) {
    __shared__ float red[8][32];
    const int tid = threadIdx.x;
    const int oo = tid & 31;
    const int kl = tid >> 5;
    const int o = blockIdx.x * 32 + oo;

    // 4 independent accumulation chains -> 4 loads in flight per thread
    float s0 = 0.f, s1 = 0.f, s2 = 0.f, s3 = 0.f;
    for (int k = kl; k + 24 < NB; k += 32) {
        s0 += psum[(size_t)(k)      * (CLS * DIM) + o];
        s1 += psum[(size_t)(k + 8)  * (CLS * DIM) + o];
        s2 += psum[(size_t)(k + 16) * (CLS * DIM) + o];
        s3 += psum[(size_t)(k + 24) * (CLS * DIM) + o];
    }
    red[kl][oo] = (s0 + s1) + (s2 + s3);
    __syncthreads();
    if (tid < 32) {
        float t = 0.f;
        for (int k = 0; k < 8; ++k) t += red[k][tid];
        fsum[o] = t;
    }

    if (blockIdx.x == 0) {
        if (tid >= 64 && tid < 128) {
            const int c = tid - 64;
            float t0 = 0.f, t1 = 0.f, t2 = 0.f, t3 = 0.f;
            for (int k = 0; k + 3 < NB; k += 4) {
                t0 += pcnt[(k)     * CLS + c];
                t1 += pcnt[(k + 1) * CLS + c];
                t2 += pcnt[(k + 2) * CLS + c];
                t3 += pcnt[(k + 3) * CLS + c];
            }
            fcnt[c] = (t0 + t1) + (t2 + t3);
        }
        if (tid >= 128 && tid < 192) {
            const int lane = tid - 128;
            float t = 0.f;
            for (int k = lane; k < NB; k += 64) t += psq[k];
            for (int off = 32; off > 0; off >>= 1) t += __shfl_down(t, off, 64);
            if (lane == 0) fsq[0] = t;
        }
    }
}

// ---------------- Phase C: centers, l2 identity, pairwise margin via Gram ----------------
__device__ double blockReduceD(double v, double* scratch, int tid) {
    for (int o = 32; o > 0; o >>= 1) v += __shfl_down(v, o, 64);
    if ((tid & 63) == 0) scratch[tid >> 6] = v;
    __syncthreads();
    double t = 0.0;
    if (tid == 0) {
        for (int i = 0; i < 16; ++i) t += scratch[i];
    }
    __syncthreads();
    return t;
}

__global__ __launch_bounds__(1024) void phaseC(const float* __restrict__ fsum,
                                               const float* __restrict__ fcnt,
                                               const float* __restrict__ fsq,
                                               float* __restrict__ out) {
    __shared__ float cenT[DIM][CLS];   // transposed centers: conflict-free column access
    __shared__ float nrm[CLS];
    __shared__ float cInv[CLS];
    __shared__ float cRaw[CLS];
    __shared__ double scratch[16];
    const int tid = threadIdx.x;

    if (tid < CLS) {
        float c = fcnt[tid];
        cRaw[tid] = c;
        cInv[tid] = 1.f / (c + EPSF);
    }
    __syncthreads();

    double s1 = 0.0, s2 = 0.0;
    for (int i = tid; i < CLS * DIM; i += 1024) {
        const int c = i >> 7;
        const int d = i & 127;
        float v = fsum[i];
        float ctr = v * cInv[c];
        cenT[d][c] = ctr;
        s1 += (double)(v * ctr);
        s2 += (double)(cRaw[c] * ctr * ctr);
    }
    const double s1t = blockReduceD(s1, scratch, tid);   // internal syncs make cenT visible
    const double s2t = blockReduceD(s2, scratch, tid);

    // per-class squared norms
    if (tid < CLS) {
        float n = 0.f;
        for (int d = 0; d < DIM; ++d) {
            float v = cenT[d][tid];
            n += v * v;
        }
        nrm[tid] = n;
    }
    __syncthreads();

    // Gram: wave w handles rows a = w, w+16, w+32, w+48 against all b = lane
    const int w = tid >> 6;
    const int b = tid & 63;
    float g0 = 0.f, g1 = 0.f, g2 = 0.f, g3 = 0.f;
    for (int d = 0; d < DIM; ++d) {
        float vb = cenT[d][b];               // coalesced, conflict-free
        g0 += cenT[d][w]      * vb;          // wave-uniform -> broadcast
        g1 += cenT[d][w + 16] * vb;
        g2 += cenT[d][w + 32] * vb;
        g3 += cenT[d][w + 48] * vb;
    }
    float ccp = 0.f;
    {
        float gs[4] = {g0, g1, g2, g3};
#pragma unroll
        for (int j = 0; j < 4; ++j) {
            const int a = w + 16 * j;
            if (a == b) continue;
            float d2 = nrm[a] + nrm[b] - 2.f * gs[j];
            float val = fmaxf(MARGIN - sqrtf(fmaxf(d2, 0.f) + EPSF), 0.f);
            ccp += val * val;
        }
    }
    const double ccOrd = blockReduceD((double)ccp, scratch, tid);

    if (tid == 0) {
        double triu = ccOrd * 0.5;                     // ordered pairs -> a<b
        double ccv = triu / 64.0 * 63.0 / 2.0;
        double l2 = ((double)fsq[0] - 2.0 * s1t + s2t) / (double)NROWS;
        out[0] = (float)(l2 + ccv);
    }
}

extern "C" void kernel_launch(void* const* d_in, const int* in_sizes, int n_in,
                              void* d_out, int out_size, void* d_ws, size_t ws_size,
                              hipStream_t stream) {
    const float* emb = (const float*)d_in[0];
    const int* tgt = (const int*)d_in[1];
    float* out = (float*)d_out;

    char* ws = (char*)d_ws;
    float* fsum = (float*)ws;             // 8192 floats
    float* fcnt = fsum + CLS * DIM;       // 64 floats
    float* fsq = fcnt + CLS;              // 1 float

    int NB = 1024;
    while (NB > 1) {
        size_t need = 65536 + (size_t)NB * ((size_t)CLS * DIM * 4 + CLS * 4 + 4);
        if (need <= ws_size) break;
        NB >>= 1;
    }
    float* psum = (float*)(ws + 65536);
    float* pcnt = psum + (size_t)NB * CLS * DIM;
    float* psq = pcnt + (size_t)NB * CLS;
    const int rowsPerBlock = NROWS / NB;

    phaseA<<<NB, 256, 0, stream>>>(emb, tgt, psum, pcnt, psq, rowsPerBlock);
    phaseB<<<256, 256, 0, stream>>>(psum, pcnt, psq, fsum, fcnt, fsq, NB);
    phaseC<<<1, 1024, 0, stream>>>(fsum, fcnt, fsq, out);
}

// Round 3
// 82.179 us; speedup vs baseline: 3.9798x; 1.5289x over previous
//
#include <hip/hip_runtime.h>

#define CLS 64
#define DIM 128
#define NROWS 262144
#define MARGIN 1.4f
#define EPSF 1e-6f
#define FIXSCALE 2097152.0f        // 2^21 (sum fixed point; |class sum|*2^21 < 2^31)
#define INVFIX (1.0f / 2097152.0f)
#define SQSCALE 1048576.0          // 2^20 (sumsq fixed point, u64)
#define INVSQ (1.0 / 1048576.0)
#define NB 1024

// ---------------- zero kernel: re-init global accumulators every call ----------------
__global__ __launch_bounds__(256) void zeroK(int* __restrict__ p, int n) {
    int i = blockIdx.x * 256 + threadIdx.x;
    if (i < n) p[i] = 0;
}

// ---------------- Phase A: LDS int accumulation -> global int atomics ----------------
__global__ __launch_bounds__(256, 4) void phaseA(const float* __restrict__ emb,
                                                 const int* __restrict__ tgt,
                                                 int* __restrict__ fsum_i,
                                                 int* __restrict__ fcnt_i,
                                                 unsigned long long* __restrict__ sq64,
                                                 int rowsPerBlock) {
    __shared__ int acc[CLS * DIM];
    __shared__ int cnt[CLS];
    __shared__ float red[4];
    const int tid = threadIdx.x;

    for (int i = tid; i < CLS * DIM; i += 256) acc[i] = 0;
    if (tid < CLS) cnt[tid] = 0;
    __syncthreads();

    const int dl = tid & 31;               // dim-lane (covers 4 dims via float4)
    const int rowBase = blockIdx.x * rowsPerBlock;
    const int iters = rowsPerBlock >> 4;   // 16 rows per iteration
    int r = rowBase + (tid >> 5);          // row-lane 0..7

    const float4* __restrict__ embv = reinterpret_cast<const float4*>(emb);

    float4 va = embv[(size_t)r * 32 + dl];
    float4 vb = embv[(size_t)(r + 8) * 32 + dl];
    int ca = tgt[r];
    int cb = tgt[r + 8];

    float sq = 0.f;
    for (int it = 0; it < iters; ++it) {
        float4 xa = va, xb = vb;
        int ka = ca, kb = cb;
        int rn = r + 16;
        if (it + 1 < iters) {
            va = embv[(size_t)rn * 32 + dl];
            vb = embv[(size_t)(rn + 8) * 32 + dl];
            ca = tgt[rn];
            cb = tgt[rn + 8];
        }
        r = rn;

        sq += xa.x * xa.x + xa.y * xa.y + xa.z * xa.z + xa.w * xa.w;
        sq += xb.x * xb.x + xb.y * xb.y + xb.z * xb.z + xb.w * xb.w;

        int* rowA = &acc[ka * DIM];
        atomicAdd(&rowA[dl],      __float2int_rn(xa.x * FIXSCALE));
        atomicAdd(&rowA[32 + dl], __float2int_rn(xa.y * FIXSCALE));
        atomicAdd(&rowA[64 + dl], __float2int_rn(xa.z * FIXSCALE));
        atomicAdd(&rowA[96 + dl], __float2int_rn(xa.w * FIXSCALE));
        int* rowB = &acc[kb * DIM];
        atomicAdd(&rowB[dl],      __float2int_rn(xb.x * FIXSCALE));
        atomicAdd(&rowB[32 + dl], __float2int_rn(xb.y * FIXSCALE));
        atomicAdd(&rowB[64 + dl], __float2int_rn(xb.z * FIXSCALE));
        atomicAdd(&rowB[96 + dl], __float2int_rn(xb.w * FIXSCALE));
        if (dl == 0) {
            atomicAdd(&cnt[ka], 1);
            atomicAdd(&cnt[kb], 1);
        }
    }

    // wave reduce sumsq, then block reduce via LDS
    for (int o = 32; o > 0; o >>= 1) sq += __shfl_down(sq, o, 64);
    if ((tid & 63) == 0) red[tid >> 6] = sq;
    __syncthreads();

    // flush LDS accumulators straight to global int accumulators (associative -> deterministic)
    for (int i = tid; i < CLS * DIM; i += 256) {
        int v = acc[i];
        if (v != 0) atomicAdd(&fsum_i[i], v);
    }
    if (tid < CLS) {
        int c = cnt[tid];
        if (c != 0) atomicAdd(&fcnt_i[tid], c);
    }
    if (tid == 0) {
        double s = (double)red[0] + (double)red[1] + (double)red[2] + (double)red[3];
        atomicAdd(sq64, (unsigned long long)(s * SQSCALE + 0.5));
    }
}

// ---------------- Phase C: centers, l2 identity, pairwise margin via Gram ----------------
__device__ double blockReduceD(double v, double* scratch, int tid) {
    for (int o = 32; o > 0; o >>= 1) v += __shfl_down(v, o, 64);
    if ((tid & 63) == 0) scratch[tid >> 6] = v;
    __syncthreads();
    double t = 0.0;
    if (tid == 0) {
        for (int i = 0; i < 16; ++i) t += scratch[i];
    }
    __syncthreads();
    return t;
}

__global__ __launch_bounds__(1024) void phaseC(const int* __restrict__ fsum_i,
                                               const int* __restrict__ fcnt_i,
                                               const unsigned long long* __restrict__ sq64,
                                               float* __restrict__ out) {
    __shared__ float cenT[DIM][CLS];   // transposed centers: conflict-free column access
    __shared__ float nrm[CLS];
    __shared__ float cInv[CLS];
    __shared__ float cRaw[CLS];
    __shared__ double scratch[16];
    const int tid = threadIdx.x;

    if (tid < CLS) {
        float c = (float)fcnt_i[tid];
        cRaw[tid] = c;
        cInv[tid] = 1.f / (c + EPSF);
    }
    __syncthreads();

    double s1 = 0.0, s2 = 0.0;
    for (int i = tid; i < CLS * DIM; i += 1024) {
        const int c = i >> 7;
        const int d = i & 127;
        float v = (float)fsum_i[i] * INVFIX;
        float ctr = v * cInv[c];
        cenT[d][c] = ctr;
        s1 += (double)(v * ctr);
        s2 += (double)(cRaw[c] * ctr * ctr);
    }
    const double s1t = blockReduceD(s1, scratch, tid);   // internal syncs make cenT visible
    const double s2t = blockReduceD(s2, scratch, tid);

    // per-class squared norms
    if (tid < CLS) {
        float n = 0.f;
        for (int d = 0; d < DIM; ++d) {
            float v = cenT[d][tid];
            n += v * v;
        }
        nrm[tid] = n;
    }
    __syncthreads();

    // Gram: wave w handles rows a = w, w+16, w+32, w+48 against all b = lane
    const int w = tid >> 6;
    const int b = tid & 63;
    float g0 = 0.f, g1 = 0.f, g2 = 0.f, g3 = 0.f;
    for (int d = 0; d < DIM; ++d) {
        float vb = cenT[d][b];               // coalesced, conflict-free
        g0 += cenT[d][w]      * vb;          // wave-uniform -> broadcast
        g1 += cenT[d][w + 16] * vb;
        g2 += cenT[d][w + 32] * vb;
        g3 += cenT[d][w + 48] * vb;
    }
    float ccp = 0.f;
    {
        float gs[4] = {g0, g1, g2, g3};
#pragma unroll
        for (int j = 0; j < 4; ++j) {
            const int a = w + 16 * j;
            if (a == b) continue;
            float d2 = nrm[a] + nrm[b] - 2.f * gs[j];
            float val = fmaxf(MARGIN - sqrtf(fmaxf(d2, 0.f) + EPSF), 0.f);
            ccp += val * val;
        }
    }
    const double ccOrd = blockReduceD((double)ccp, scratch, tid);

    if (tid == 0) {
        double triu = ccOrd * 0.5;                     // ordered pairs -> a<b
        double ccv = triu / 64.0 * 63.0 / 2.0;
        double fsq = (double)sq64[0] * INVSQ;
        double l2 = (fsq - 2.0 * s1t + s2t) / (double)NROWS;
        out[0] = (float)(l2 + ccv);
    }
}

extern "C" void kernel_launch(void* const* d_in, const int* in_sizes, int n_in,
                              void* d_out, int out_size, void* d_ws, size_t ws_size,
                              hipStream_t stream) {
    const float* emb = (const float*)d_in[0];
    const int* tgt = (const int*)d_in[1];
    float* out = (float*)d_out;

    char* ws = (char*)d_ws;
    int* fsum_i = (int*)ws;                                  // 8192 ints
    int* fcnt_i = fsum_i + CLS * DIM;                        // 64 ints
    unsigned long long* sq64 = (unsigned long long*)(ws + 33024); // 8B, aligned

    const int nZero = CLS * DIM + CLS + 2;                   // 8258 dwords
    const int rowsPerBlock = NROWS / NB;                     // 256

    zeroK<<<(nZero + 255) / 256, 256, 0, stream>>>(fsum_i, nZero);
    phaseA<<<NB, 256, 0, stream>>>(emb, tgt, fsum_i, fcnt_i, sq64, rowsPerBlock);
    phaseC<<<1, 1024, 0, stream>>>(fsum_i, fcnt_i, sq64, out);
}

// Round 4
// 55.402 us; speedup vs baseline: 5.9033x; 1.4833x over previous
//
#include <hip/hip_runtime.h>

#define CLS 64
#define DIM 128
#define NROWS 262144
#define MARGIN 1.4f
#define EPSF 1e-6f
#define FIXSCALE 1048576.0f        // 2^20 (sum fixed point)
#define INVFIX (1.0f / 1048576.0f)
#define SQSCALE 1048576.0          // 2^20 (sumsq fixed point, u64)
#define INVSQ (1.0 / 1048576.0)
#define NB 256                     // one 512-thread block per CU

// ---------------- zero kernel: re-init global accumulators every call ----------------
__global__ __launch_bounds__(256) void zeroK(int* __restrict__ p, int n) {
    int i = blockIdx.x * 256 + threadIdx.x;
    if (i < n) p[i] = 0;
}

// ---------------- Phase A: LDS int accumulation -> global int atomics ----------------
__global__ __launch_bounds__(512, 2) void phaseA(const float* __restrict__ emb,
                                                 const int* __restrict__ tgt,
                                                 int* __restrict__ fsum_i,
                                                 int* __restrict__ fcnt_i,
                                                 unsigned long long* __restrict__ sq64,
                                                 int rowsPerBlock) {
    __shared__ int acc[CLS * DIM];
    __shared__ int cnt[CLS];
    __shared__ float red[8];
    const int tid = threadIdx.x;

    for (int i = tid; i < CLS * DIM; i += 512) acc[i] = 0;
    if (tid < CLS) cnt[tid] = 0;
    __syncthreads();

    const int dl = tid & 31;               // dim-lane (covers 4 dims via float4)
    const int rl = tid >> 5;               // row-lane 0..15
    const int rowBase = blockIdx.x * rowsPerBlock;
    const int iters = rowsPerBlock >> 6;   // 64 rows per iteration
    int r = rowBase + rl;

    const float4* __restrict__ embv = reinterpret_cast<const float4*>(emb);

    // 4-deep prefetch: rows r, r+16, r+32, r+48
    float4 v0 = embv[(size_t)(r)      * 32 + dl];
    float4 v1 = embv[(size_t)(r + 16) * 32 + dl];
    float4 v2 = embv[(size_t)(r + 32) * 32 + dl];
    float4 v3 = embv[(size_t)(r + 48) * 32 + dl];
    int c0 = tgt[r];
    int c1 = tgt[r + 16];
    int c2 = tgt[r + 32];
    int c3 = tgt[r + 48];

    float sq = 0.f;
    for (int it = 0; it < iters; ++it) {
        float4 x0 = v0, x1 = v1, x2 = v2, x3 = v3;
        int k0 = c0, k1 = c1, k2 = c2, k3 = c3;
        int rn = r + 64;
        if (it + 1 < iters) {
            v0 = embv[(size_t)(rn)      * 32 + dl];
            v1 = embv[(size_t)(rn + 16) * 32 + dl];
            v2 = embv[(size_t)(rn + 32) * 32 + dl];
            v3 = embv[(size_t)(rn + 48) * 32 + dl];
            c0 = tgt[rn];
            c1 = tgt[rn + 16];
            c2 = tgt[rn + 32];
            c3 = tgt[rn + 48];
        }
        r = rn;

        sq += x0.x * x0.x + x0.y * x0.y + x0.z * x0.z + x0.w * x0.w;
        sq += x1.x * x1.x + x1.y * x1.y + x1.z * x1.z + x1.w * x1.w;
        sq += x2.x * x2.x + x2.y * x2.y + x2.z * x2.z + x2.w * x2.w;
        sq += x3.x * x3.x + x3.y * x3.y + x3.z * x3.z + x3.w * x3.w;

        int* row0 = &acc[k0 * DIM];
        atomicAdd(&row0[dl],      __float2int_rn(x0.x * FIXSCALE));
        atomicAdd(&row0[32 + dl], __float2int_rn(x0.y * FIXSCALE));
        atomicAdd(&row0[64 + dl], __float2int_rn(x0.z * FIXSCALE));
        atomicAdd(&row0[96 + dl], __float2int_rn(x0.w * FIXSCALE));
        int* row1 = &acc[k1 * DIM];
        atomicAdd(&row1[dl],      __float2int_rn(x1.x * FIXSCALE));
        atomicAdd(&row1[32 + dl], __float2int_rn(x1.y * FIXSCALE));
        atomicAdd(&row1[64 + dl], __float2int_rn(x1.z * FIXSCALE));
        atomicAdd(&row1[96 + dl], __float2int_rn(x1.w * FIXSCALE));
        int* row2 = &acc[k2 * DIM];
        atomicAdd(&row2[dl],      __float2int_rn(x2.x * FIXSCALE));
        atomicAdd(&row2[32 + dl], __float2int_rn(x2.y * FIXSCALE));
        atomicAdd(&row2[64 + dl], __float2int_rn(x2.z * FIXSCALE));
        atomicAdd(&row2[96 + dl], __float2int_rn(x2.w * FIXSCALE));
        int* row3 = &acc[k3 * DIM];
        atomicAdd(&row3[dl],      __float2int_rn(x3.x * FIXSCALE));
        atomicAdd(&row3[32 + dl], __float2int_rn(x3.y * FIXSCALE));
        atomicAdd(&row3[64 + dl], __float2int_rn(x3.z * FIXSCALE));
        atomicAdd(&row3[96 + dl], __float2int_rn(x3.w * FIXSCALE));
        if (dl == 0) {
            atomicAdd(&cnt[k0], 1);
            atomicAdd(&cnt[k1], 1);
            atomicAdd(&cnt[k2], 1);
            atomicAdd(&cnt[k3], 1);
        }
    }

    // wave reduce sumsq, then block reduce via LDS
    for (int o = 32; o > 0; o >>= 1) sq += __shfl_down(sq, o, 64);
    if ((tid & 63) == 0) red[tid >> 6] = sq;
    __syncthreads();

    // flush LDS accumulators straight to global int accumulators (associative -> deterministic)
    for (int i = tid; i < CLS * DIM; i += 512) atomicAdd(&fsum_i[i], acc[i]);
    if (tid < CLS) atomicAdd(&fcnt_i[tid], cnt[tid]);
    if (tid == 0) {
        double s = 0.0;
        for (int k = 0; k < 8; ++k) s += (double)red[k];
        atomicAdd(sq64, (unsigned long long)(s * SQSCALE + 0.5));
    }
}

// ---------------- Phase C: centers, l2 identity, pairwise margin via Gram ----------------
__device__ double blockReduceD(double v, double* scratch, int tid) {
    for (int o = 32; o > 0; o >>= 1) v += __shfl_down(v, o, 64);
    if ((tid & 63) == 0) scratch[tid >> 6] = v;
    __syncthreads();
    double t = 0.0;
    if (tid == 0) {
        for (int i = 0; i < 16; ++i) t += scratch[i];
    }
    __syncthreads();
    return t;
}

__global__ __launch_bounds__(1024) void phaseC(const int* __restrict__ fsum_i,
                                               const int* __restrict__ fcnt_i,
                                               const unsigned long long* __restrict__ sq64,
                                               float* __restrict__ out) {
    __shared__ float cenT[DIM][CLS];   // transposed centers: conflict-free column access
    __shared__ float nrm[CLS];
    __shared__ float cInv[CLS];
    __shared__ float cRaw[CLS];
    __shared__ double scratch[16];
    const int tid = threadIdx.x;

    if (tid < CLS) {
        float c = (float)fcnt_i[tid];
        cRaw[tid] = c;
        cInv[tid] = 1.f / (c + EPSF);
    }
    __syncthreads();

    double s1 = 0.0, s2 = 0.0;
    for (int i = tid; i < CLS * DIM; i += 1024) {
        const int c = i >> 7;
        const int d = i & 127;
        float v = (float)fsum_i[i] * INVFIX;
        float ctr = v * cInv[c];
        cenT[d][c] = ctr;
        s1 += (double)(v * ctr);
        s2 += (double)(cRaw[c] * ctr * ctr);
    }
    const double s1t = blockReduceD(s1, scratch, tid);   // internal syncs make cenT visible
    const double s2t = blockReduceD(s2, scratch, tid);

    // per-class squared norms
    if (tid < CLS) {
        float n = 0.f;
        for (int d = 0; d < DIM; ++d) {
            float v = cenT[d][tid];
            n += v * v;
        }
        nrm[tid] = n;
    }
    __syncthreads();

    // Gram: wave w handles rows a = w, w+16, w+32, w+48 against all b = lane
    const int w = tid >> 6;
    const int b = tid & 63;
    float g0 = 0.f, g1 = 0.f, g2 = 0.f, g3 = 0.f;
    for (int d = 0; d < DIM; ++d) {
        float vb = cenT[d][b];               // coalesced, conflict-free
        g0 += cenT[d][w]      * vb;          // wave-uniform -> broadcast
        g1 += cenT[d][w + 16] * vb;
        g2 += cenT[d][w + 32] * vb;
        g3 += cenT[d][w + 48] * vb;
    }
    float ccp = 0.f;
    {
        float gs[4] = {g0, g1, g2, g3};
#pragma unroll
        for (int j = 0; j < 4; ++j) {
            const int a = w + 16 * j;
            if (a == b) continue;
            float d2 = nrm[a] + nrm[b] - 2.f * gs[j];
            float val = fmaxf(MARGIN - sqrtf(fmaxf(d2, 0.f) + EPSF), 0.f);
            ccp += val * val;
        }
    }
    const double ccOrd = blockReduceD((double)ccp, scratch, tid);

    if (tid == 0) {
        double triu = ccOrd * 0.5;                     // ordered pairs -> a<b
        double ccv = triu / 64.0 * 63.0 / 2.0;
        double fsq = (double)sq64[0] * INVSQ;
        double l2 = (fsq - 2.0 * s1t + s2t) / (double)NROWS;
        out[0] = (float)(l2 + ccv);
    }
}

extern "C" void kernel_launch(void* const* d_in, const int* in_sizes, int n_in,
                              void* d_out, int out_size, void* d_ws, size_t ws_size,
                              hipStream_t stream) {
    const float* emb = (const float*)d_in[0];
    const int* tgt = (const int*)d_in[1];
    float* out = (float*)d_out;

    char* ws = (char*)d_ws;
    int* fsum_i = (int*)ws;                                  // 8192 ints
    int* fcnt_i = fsum_i + CLS * DIM;                        // 64 ints
    unsigned long long* sq64 = (unsigned long long*)(ws + 33024); // 8B, aligned

    const int nZero = CLS * DIM + CLS + 2;                   // 8258 dwords
    const int rowsPerBlock = NROWS / NB;                     // 1024

    zeroK<<<(nZero + 255) / 256, 256, 0, stream>>>(fsum_i, nZero);
    phaseA<<<NB, 512, 0, stream>>>(emb, tgt, fsum_i, fcnt_i, sq64, rowsPerBlock);
    phaseC<<<1, 1024, 0, stream>>>(fsum_i, fcnt_i, sq64, out);
}